// Round 1
// baseline (215.617 us; speedup 1.0000x reference)
//
#include <hip/hip_runtime.h>
#include <math.h>

namespace {
constexpr int Bn = 2, CF = 64, CHN = 32;
constexpr int H = 256, W = 256, HW = H * W;
constexpr int IH = 512, IW = 512;

// ws layout in floats
constexpr int OFF_M   = 0;                   // 256*256 = 65536
constexpr int OFF_GXX = OFF_M + 256 * 256;   // 256*3
constexpr int OFF_GYY = OFF_GXX + 256 * 3;   // 256*3
constexpr int OFF_EM  = OFF_GYY + 256 * 3;   // = 67072 (byte off 268288, 16B aligned)
constexpr int OFF_S   = OFF_EM + Bn * CHN * HW;  // Bn*HW
// total floats = 67072 + 4194304 + 131072 = 4392448  (~17.6 MB)
}

// ---------------------------------------------------------------------------
// Kernel P: positional Gram tables.
// PX[o][a] = sum_i wpos[o][2i]*sin(a*div_i) + wpos[o][2i+1]*cos(a*div_i)
// PY[o][t] likewise with wpos[o][32+...]
// M[a][t]   = dot_o(PX[:,a], PY[:,t])
// GXX[a][j] = dot_o(PX[:,a], PX[:,a+2(j-1)])   (0 if OOB; never read then)
// GYY[a][j] = dot_o(PY[:,a], PY[:,a+2(j-1)])
// ---------------------------------------------------------------------------
__global__ __launch_bounds__(256) void pos_gram_kernel(
    const float* __restrict__ w_pos,
    float* __restrict__ M, float* __restrict__ GXX, float* __restrict__ GYY)
{
  __shared__ float PYs[32][256];
  const int t = threadIdx.x;   // y-coordinate for PY / M column
  const int a = blockIdx.x;    // x-coordinate for PX / M row

  float divs[16], syi[16], cyi[16], sxa[16], cxa[16];
#pragma unroll
  for (int i = 0; i < 16; i++) {
    divs[i] = expf((float)(2 * i) * (-0.2878231366242557f)); // -ln(1e4)/32
    float ay = (float)t * divs[i];
    syi[i] = sinf(ay); cyi[i] = cosf(ay);
    float ax = (float)a * divs[i];
    sxa[i] = sinf(ax); cxa[i] = cosf(ax);
  }

  float pxa[32];
#pragma unroll
  for (int o = 0; o < 32; o++) {
    float accY = 0.f, accX = 0.f;
    const float* wr = w_pos + o * 64;
#pragma unroll
    for (int i = 0; i < 16; i++) {
      accX += wr[2 * i] * sxa[i] + wr[2 * i + 1] * cxa[i];
      accY += wr[32 + 2 * i] * syi[i] + wr[33 + 2 * i] * cyi[i];
    }
    PYs[o][t] = accY;
    pxa[o] = accX;
  }
  __syncthreads();

  float m = 0.f;
#pragma unroll
  for (int o = 0; o < 32; o++) m += pxa[o] * PYs[o][t];
  M[a * 256 + t] = m;

  if (t < 3) {
    int nb = a + 2 * (t - 1);
    float g = 0.f;
    if (nb >= 0 && nb < 256) {
#pragma unroll
      for (int o = 0; o < 32; o++) g += PYs[o][a] * PYs[o][nb];
    }
    GYY[a * 3 + t] = g;
  } else if (t < 6) {
    int j = t - 3;
    int nb = a + 2 * (j - 1);
    float g = 0.f;
    if (nb >= 0 && nb < 256) {
      float s2[16], c2[16];
#pragma unroll
      for (int i = 0; i < 16; i++) {
        float ax = (float)nb * divs[i];
        s2[i] = sinf(ax); c2[i] = cosf(ax);
      }
#pragma unroll
      for (int o = 0; o < 32; o++) {
        float accX = 0.f;
        const float* wr = w_pos + o * 64;
#pragma unroll
        for (int i = 0; i < 16; i++)
          accX += wr[2 * i] * s2[i] + wr[2 * i + 1] * c2[i];
        g += pxa[o] * accX;
      }
    }
    GXX[a * 3 + j] = g;
  }
}

// ---------------------------------------------------------------------------
// Kernel 1: em_img (channel-last [b][pix][32]) + smap.
// em_img[b,pix,o] = sum_c w_img[o,c] * rimg[b,c,pix]  (rimg = antialiased 2x
// downsample of img: separable [1,3,3,1]/8, edges [3,3,1]/7)
// smap[b,pix] = dot_c(inp[b,:,pix], w_comp)
// ---------------------------------------------------------------------------
__device__ __forceinline__ void resize_taps(int p, int n, float w[4], int idx[4])
{
#pragma unroll
  for (int r = 0; r < 4; r++) {
    int q = 2 * p - 1 + r;
    idx[r] = min(max(q, 0), 2 * n - 1);
  }
  if (p == 0)          { w[0] = 0.f;        w[1] = 3.f / 7.f; w[2] = 3.f / 7.f; w[3] = 1.f / 7.f; }
  else if (p == n - 1) { w[0] = 1.f / 7.f;  w[1] = 3.f / 7.f; w[2] = 3.f / 7.f; w[3] = 0.f; }
  else                 { w[0] = 0.125f;     w[1] = 0.375f;    w[2] = 0.375f;    w[3] = 0.125f; }
}

__global__ __launch_bounds__(256) void em_s_kernel(
    const float* __restrict__ inp, const float* __restrict__ img,
    const float* __restrict__ w_img, const float* __restrict__ w_comp,
    float* __restrict__ em, float* __restrict__ smap)
{
  const int x = blockIdx.x * 64 + threadIdx.x;
  const int y = blockIdx.y * 4 + threadIdx.y;
  const int b = blockIdx.z;
  const int pix = y * W + x;

  float wy[4], wx[4];
  int ry[4], rx[4];
  resize_taps(y, H, wy, ry);
  resize_taps(x, W, wx, rx);

  float rimg[3];
#pragma unroll
  for (int c = 0; c < 3; c++) {
    const float* ip = img + ((b * 3 + c) * IH) * IW;
    float acc = 0.f;
#pragma unroll
    for (int r = 0; r < 4; r++) {
      const float* rowp = ip + ry[r] * IW;
      float rs = wx[0] * rowp[rx[0]] + wx[1] * rowp[rx[1]] +
                 wx[2] * rowp[rx[2]] + wx[3] * rowp[rx[3]];
      acc += wy[r] * rs;
    }
    rimg[c] = acc;
  }

  float* ep = em + ((size_t)b * HW + pix) * CHN;
#pragma unroll
  for (int o8 = 0; o8 < 8; o8++) {
    float4 v;
    v.x = w_img[(4 * o8 + 0) * 3] * rimg[0] + w_img[(4 * o8 + 0) * 3 + 1] * rimg[1] + w_img[(4 * o8 + 0) * 3 + 2] * rimg[2];
    v.y = w_img[(4 * o8 + 1) * 3] * rimg[0] + w_img[(4 * o8 + 1) * 3 + 1] * rimg[1] + w_img[(4 * o8 + 1) * 3 + 2] * rimg[2];
    v.z = w_img[(4 * o8 + 2) * 3] * rimg[0] + w_img[(4 * o8 + 2) * 3 + 1] * rimg[1] + w_img[(4 * o8 + 2) * 3 + 2] * rimg[2];
    v.w = w_img[(4 * o8 + 3) * 3] * rimg[0] + w_img[(4 * o8 + 3) * 3 + 1] * rimg[1] + w_img[(4 * o8 + 3) * 3 + 2] * rimg[2];
    ((float4*)ep)[o8] = v;
  }

  const float* inpb = inp + (size_t)b * CF * HW;
  float s = 0.f;
#pragma unroll
  for (int c = 0; c < CF; c++) s += inpb[c * HW + pix] * w_comp[c];
  smap[b * HW + pix] = s;
}

// ---------------------------------------------------------------------------
// Kernel 2: phi + weighted gather.
// phi[k] = sigmoid(smap[nb_k]) * ( dot32(em_img[nb_k], em_img[ctr])
//          + GXX[x,kx] + GYY[y,ky] + M[nx,y] + M[x,ny] )      (0 if OOB)
// out[b,c,pix] = sum_k phi[k] * inp[b,c,nb_k]
// ---------------------------------------------------------------------------
__global__ __launch_bounds__(512) void main_kernel(
    const float* __restrict__ inp, const float* __restrict__ em,
    const float* __restrict__ smap, const float* __restrict__ M,
    const float* __restrict__ GXX, const float* __restrict__ GYY,
    float* __restrict__ out)
{
  const int x = blockIdx.x * 64 + threadIdx.x;
  const int y = blockIdx.y * 8 + threadIdx.y;
  const int b = blockIdx.z;
  const int pix = y * W + x;

  const float* emb  = em + (size_t)b * HW * CHN;
  const float* inpb = inp + (size_t)b * CF * HW;
  const float* sb   = smap + b * HW;

  float emc[32];
  const float4* ecp = (const float4*)(emb + (size_t)pix * CHN);
#pragma unroll
  for (int i = 0; i < 8; i++) {
    float4 v = ecp[i];
    emc[4 * i] = v.x; emc[4 * i + 1] = v.y; emc[4 * i + 2] = v.z; emc[4 * i + 3] = v.w;
  }

  float phi[9];
  int npix[9];
#pragma unroll
  for (int k = 0; k < 9; k++) {
    const int ky = k / 3, kx = k % 3;
    const int ny = y + 2 * (ky - 1), nx = x + 2 * (kx - 1);
    const bool valid = (ny >= 0) & (ny < H) & (nx >= 0) & (nx < W);
    const int cny = min(max(ny, 0), H - 1);
    const int cnx = min(max(nx, 0), W - 1);
    const int np = cny * W + cnx;
    npix[k] = np;

    float fs = 0.f;
    const float4* enp = (const float4*)(emb + (size_t)np * CHN);
#pragma unroll
    for (int i = 0; i < 8; i++) {
      float4 v = enp[i];
      fs += v.x * emc[4 * i] + v.y * emc[4 * i + 1] + v.z * emc[4 * i + 2] + v.w * emc[4 * i + 3];
    }
    fs += GXX[x * 3 + kx] + GYY[y * 3 + ky] + M[cnx * 256 + y] + M[x * 256 + cny];

    const float s = sb[np];
    const float cs = 1.f / (1.f + expf(-s));
    phi[k] = valid ? cs * fs : 0.f;
  }

  float* outb = out + (size_t)b * CF * HW;
#pragma unroll 2
  for (int c = 0; c < CF; c++) {
    const float* ic = inpb + c * HW;
    float acc = phi[0] * ic[npix[0]];
#pragma unroll
    for (int k = 1; k < 9; k++) acc += phi[k] * ic[npix[k]];
    outb[c * HW + pix] = acc;
  }
}

// ---------------------------------------------------------------------------
extern "C" void kernel_launch(void* const* d_in, const int* in_sizes, int n_in,
                              void* d_out, int out_size, void* d_ws, size_t ws_size,
                              hipStream_t stream)
{
  const float* inp    = (const float*)d_in[0];
  const float* img    = (const float*)d_in[1];
  const float* w_pos  = (const float*)d_in[2];
  const float* w_img  = (const float*)d_in[3];
  const float* w_comp = (const float*)d_in[4];
  float* out = (float*)d_out;
  float* ws  = (float*)d_ws;

  float* M    = ws + OFF_M;
  float* GXX  = ws + OFF_GXX;
  float* GYY  = ws + OFF_GYY;
  float* em   = ws + OFF_EM;
  float* smap = ws + OFF_S;

  hipLaunchKernelGGL(pos_gram_kernel, dim3(256), dim3(256), 0, stream,
                     w_pos, M, GXX, GYY);

  dim3 blk1(64, 4, 1), g1(W / 64, H / 4, Bn);
  hipLaunchKernelGGL(em_s_kernel, g1, blk1, 0, stream,
                     inp, img, w_img, w_comp, em, smap);

  dim3 blk2(64, 8, 1), g2(W / 64, H / 8, Bn);
  hipLaunchKernelGGL(main_kernel, g2, blk2, 0, stream,
                     inp, em, smap, M, GXX, GYY, out);
}

// Round 2
// 151.227 us; speedup vs baseline: 1.4258x; 1.4258x over previous
//
#include <hip/hip_runtime.h>
#include <math.h>

namespace {
constexpr int Bn = 2, CF = 64, CHN = 32;
constexpr int H = 256, W = 256, HW = H * W;
constexpr int IH = 512, IW = 512;

// ws layout in floats
constexpr int OFF_M   = 0;                   // 256*256 = 65536
constexpr int OFF_GXX = OFF_M + 256 * 256;   // 256*3
constexpr int OFF_GYY = OFF_GXX + 256 * 3;   // 256*3
constexpr int OFF_EM  = OFF_GYY + 256 * 3;   // = 67072 (byte off 268288, 16B aligned)
constexpr int OFF_S   = OFF_EM + Bn * CHN * HW;  // Bn*HW
// PX/PY (32*256 each) OVERLAY the em region: consumed by gram_kernel before
// em_s_kernel overwrites it (same stream => ordered).
constexpr int OFF_PX  = OFF_EM;
constexpr int OFF_PY  = OFF_EM + 32 * 256;
}

// ---------------------------------------------------------------------------
// P1: PX[o][t] = sum_i wpos[o][2i]*sin(t*div_i) + wpos[o][2i+1]*cos(t*div_i)
//     PY[o][t] = same with wpos[o][32+...]
// One block per o (32 blocks); thread t covers coordinate t. Transcendentals
// computed 32x total instead of 256x-per-block as before.
// ---------------------------------------------------------------------------
__global__ __launch_bounds__(256) void pxy_kernel(
    const float* __restrict__ w_pos,
    float* __restrict__ PX, float* __restrict__ PY)
{
  const int t = threadIdx.x;
  const int o = blockIdx.x;
  float s[16], c[16];
#pragma unroll
  for (int i = 0; i < 16; i++) {
    float d = expf((float)(2 * i) * (-0.2878231366242557f)); // -ln(1e4)/32
    float a = (float)t * d;
    s[i] = sinf(a);
    c[i] = cosf(a);
  }
  const float* wr = w_pos + o * 64;
  float ax = 0.f, ay = 0.f;
#pragma unroll
  for (int i = 0; i < 16; i++) {
    ax += wr[2 * i] * s[i] + wr[2 * i + 1] * c[i];
    ay += wr[32 + 2 * i] * s[i] + wr[33 + 2 * i] * c[i];
  }
  PX[o * 256 + t] = ax;
  PY[o * 256 + t] = ay;
}

// ---------------------------------------------------------------------------
// P2: M[a][t] = dot_o(PX[:,a], PY[:,t]);
//     GXX[a][j] = dot_o(PX[:,a], PX[:,a+2(j-1)]) (0 if OOB; masked downstream)
//     GYY[a][j] likewise on PY.
// ---------------------------------------------------------------------------
__global__ __launch_bounds__(256) void gram_kernel(
    const float* __restrict__ PX, const float* __restrict__ PY,
    float* __restrict__ M, float* __restrict__ GXX, float* __restrict__ GYY)
{
  const int t = threadIdx.x;
  const int a = blockIdx.x;

  __shared__ float pxa[32], pxm[32], pxp[32], pya[32], pym[32], pyp[32];
  if (t < 32) {
    pxa[t] = PX[t * 256 + a];
    pya[t] = PY[t * 256 + a];
    pxm[t] = (a >= 2)  ? PX[t * 256 + a - 2] : 0.f;
    pxp[t] = (a < 254) ? PX[t * 256 + a + 2] : 0.f;
    pym[t] = (a >= 2)  ? PY[t * 256 + a - 2] : 0.f;
    pyp[t] = (a < 254) ? PY[t * 256 + a + 2] : 0.f;
  }
  __syncthreads();

  float m = 0.f;
#pragma unroll
  for (int o = 0; o < 32; o++) m += pxa[o] * PY[o * 256 + t];
  M[a * 256 + t] = m;

  if (t < 3) {
    const float* sel = (t == 0) ? pxm : (t == 1) ? pxa : pxp;
    float g = 0.f;
#pragma unroll
    for (int o = 0; o < 32; o++) g += pxa[o] * sel[o];
    GXX[a * 3 + t] = g;
  } else if (t < 6) {
    const int j = t - 3;
    const float* sel = (j == 0) ? pym : (j == 1) ? pya : pyp;
    float g = 0.f;
#pragma unroll
    for (int o = 0; o < 32; o++) g += pya[o] * sel[o];
    GYY[a * 3 + j] = g;
  }
}

// ---------------------------------------------------------------------------
// Kernel 1: em_img (channel-last [b][pix][32]) + smap.
// em_img[b,pix,o] = sum_c w_img[o,c] * rimg[b,c,pix]  (rimg = antialiased 2x
// downsample of img: separable [1,3,3,1]/8, edges [3,3,1]/7)
// smap[b,pix] = dot_c(inp[b,:,pix], w_comp)
// ---------------------------------------------------------------------------
__device__ __forceinline__ void resize_taps(int p, int n, float w[4], int idx[4])
{
#pragma unroll
  for (int r = 0; r < 4; r++) {
    int q = 2 * p - 1 + r;
    idx[r] = min(max(q, 0), 2 * n - 1);
  }
  if (p == 0)          { w[0] = 0.f;        w[1] = 3.f / 7.f; w[2] = 3.f / 7.f; w[3] = 1.f / 7.f; }
  else if (p == n - 1) { w[0] = 1.f / 7.f;  w[1] = 3.f / 7.f; w[2] = 3.f / 7.f; w[3] = 0.f; }
  else                 { w[0] = 0.125f;     w[1] = 0.375f;    w[2] = 0.375f;    w[3] = 0.125f; }
}

__global__ __launch_bounds__(256) void em_s_kernel(
    const float* __restrict__ inp, const float* __restrict__ img,
    const float* __restrict__ w_img, const float* __restrict__ w_comp,
    float* __restrict__ em, float* __restrict__ smap)
{
  const int x = blockIdx.x * 64 + threadIdx.x;
  const int y = blockIdx.y * 4 + threadIdx.y;
  const int b = blockIdx.z;
  const int pix = y * W + x;

  float wy[4], wx[4];
  int ry[4], rx[4];
  resize_taps(y, H, wy, ry);
  resize_taps(x, W, wx, rx);

  float rimg[3];
#pragma unroll
  for (int c = 0; c < 3; c++) {
    const float* ip = img + ((b * 3 + c) * IH) * IW;
    float acc = 0.f;
#pragma unroll
    for (int r = 0; r < 4; r++) {
      const float* rowp = ip + ry[r] * IW;
      float rs = wx[0] * rowp[rx[0]] + wx[1] * rowp[rx[1]] +
                 wx[2] * rowp[rx[2]] + wx[3] * rowp[rx[3]];
      acc += wy[r] * rs;
    }
    rimg[c] = acc;
  }

  float* ep = em + ((size_t)b * HW + pix) * CHN;
#pragma unroll
  for (int o8 = 0; o8 < 8; o8++) {
    float4 v;
    v.x = w_img[(4 * o8 + 0) * 3] * rimg[0] + w_img[(4 * o8 + 0) * 3 + 1] * rimg[1] + w_img[(4 * o8 + 0) * 3 + 2] * rimg[2];
    v.y = w_img[(4 * o8 + 1) * 3] * rimg[0] + w_img[(4 * o8 + 1) * 3 + 1] * rimg[1] + w_img[(4 * o8 + 1) * 3 + 2] * rimg[2];
    v.z = w_img[(4 * o8 + 2) * 3] * rimg[0] + w_img[(4 * o8 + 2) * 3 + 1] * rimg[1] + w_img[(4 * o8 + 2) * 3 + 2] * rimg[2];
    v.w = w_img[(4 * o8 + 3) * 3] * rimg[0] + w_img[(4 * o8 + 3) * 3 + 1] * rimg[1] + w_img[(4 * o8 + 3) * 3 + 2] * rimg[2];
    ((float4*)ep)[o8] = v;
  }

  const float* inpb = inp + (size_t)b * CF * HW;
  float s = 0.f;
#pragma unroll
  for (int c = 0; c < CF; c++) s += inpb[c * HW + pix] * w_comp[c];
  smap[b * HW + pix] = s;
}

// ---------------------------------------------------------------------------
// Kernel 2: phi + weighted gather.
// phi[k] = sigmoid(smap[nb_k]) * ( dot32(em_img[nb_k], em_img[ctr])
//          + GXX[x,kx] + GYY[y,ky] + M[nx,y] + M[x,ny] )      (0 if OOB)
// out[b,c,pix] = sum_k phi[k] * inp[b,c,nb_k]
// ---------------------------------------------------------------------------
__global__ __launch_bounds__(512) void main_kernel(
    const float* __restrict__ inp, const float* __restrict__ em,
    const float* __restrict__ smap, const float* __restrict__ M,
    const float* __restrict__ GXX, const float* __restrict__ GYY,
    float* __restrict__ out)
{
  const int x = blockIdx.x * 64 + threadIdx.x;
  const int y = blockIdx.y * 8 + threadIdx.y;
  const int b = blockIdx.z;
  const int pix = y * W + x;

  const float* emb  = em + (size_t)b * HW * CHN;
  const float* inpb = inp + (size_t)b * CF * HW;
  const float* sb   = smap + b * HW;

  float emc[32];
  const float4* ecp = (const float4*)(emb + (size_t)pix * CHN);
#pragma unroll
  for (int i = 0; i < 8; i++) {
    float4 v = ecp[i];
    emc[4 * i] = v.x; emc[4 * i + 1] = v.y; emc[4 * i + 2] = v.z; emc[4 * i + 3] = v.w;
  }

  float phi[9];
  int npix[9];
#pragma unroll
  for (int k = 0; k < 9; k++) {
    const int ky = k / 3, kx = k % 3;
    const int ny = y + 2 * (ky - 1), nx = x + 2 * (kx - 1);
    const bool valid = (ny >= 0) & (ny < H) & (nx >= 0) & (nx < W);
    const int cny = min(max(ny, 0), H - 1);
    const int cnx = min(max(nx, 0), W - 1);
    const int np = cny * W + cnx;
    npix[k] = np;

    float fs = 0.f;
    const float4* enp = (const float4*)(emb + (size_t)np * CHN);
#pragma unroll
    for (int i = 0; i < 8; i++) {
      float4 v = enp[i];
      fs += v.x * emc[4 * i] + v.y * emc[4 * i + 1] + v.z * emc[4 * i + 2] + v.w * emc[4 * i + 3];
    }
    fs += GXX[x * 3 + kx] + GYY[y * 3 + ky] + M[cnx * 256 + y] + M[x * 256 + cny];

    const float s = sb[np];
    const float cs = 1.f / (1.f + expf(-s));
    phi[k] = valid ? cs * fs : 0.f;
  }

  float* outb = out + (size_t)b * CF * HW;
#pragma unroll 2
  for (int c = 0; c < CF; c++) {
    const float* ic = inpb + c * HW;
    float acc = phi[0] * ic[npix[0]];
#pragma unroll
    for (int k = 1; k < 9; k++) acc += phi[k] * ic[npix[k]];
    outb[c * HW + pix] = acc;
  }
}

// ---------------------------------------------------------------------------
extern "C" void kernel_launch(void* const* d_in, const int* in_sizes, int n_in,
                              void* d_out, int out_size, void* d_ws, size_t ws_size,
                              hipStream_t stream)
{
  const float* inp    = (const float*)d_in[0];
  const float* img    = (const float*)d_in[1];
  const float* w_pos  = (const float*)d_in[2];
  const float* w_img  = (const float*)d_in[3];
  const float* w_comp = (const float*)d_in[4];
  float* out = (float*)d_out;
  float* ws  = (float*)d_ws;

  float* M    = ws + OFF_M;
  float* GXX  = ws + OFF_GXX;
  float* GYY  = ws + OFF_GYY;
  float* em   = ws + OFF_EM;
  float* smap = ws + OFF_S;
  float* PX   = ws + OFF_PX;   // overlays em region (consumed before em written)
  float* PY   = ws + OFF_PY;

  hipLaunchKernelGGL(pxy_kernel, dim3(32), dim3(256), 0, stream, w_pos, PX, PY);
  hipLaunchKernelGGL(gram_kernel, dim3(256), dim3(256), 0, stream,
                     PX, PY, M, GXX, GYY);

  dim3 blk1(64, 4, 1), g1(W / 64, H / 4, Bn);
  hipLaunchKernelGGL(em_s_kernel, g1, blk1, 0, stream,
                     inp, img, w_img, w_comp, em, smap);

  dim3 blk2(64, 8, 1), g2(W / 64, H / 8, Bn);
  hipLaunchKernelGGL(main_kernel, g2, blk2, 0, stream,
                     inp, em, smap, M, GXX, GYY, out);
}